// Round 8
// baseline (1921.052 us; speedup 1.0000x reference)
//
#include <hip/hip_runtime.h>
#include <hip/hip_bf16.h>
#include <stdint.h>

#define NH 8

typedef uint16_t u16;
typedef uint32_t u32;
typedef __attribute__((ext_vector_type(8))) short s8b;    // 8 bf16 (4 VGPR)
typedef __attribute__((ext_vector_type(4))) u32 u32x4;
typedef __attribute__((ext_vector_type(4))) float f32x4;
typedef __attribute__((ext_vector_type(16))) float f32x16;

#if __has_builtin(__builtin_amdgcn_exp2f)
#define EXPS(x) __builtin_amdgcn_exp2f(x)
#define QSCALE 0.36067376022224085f   // 0.25 * log2(e)
#else
#define EXPS(x) __expf(x)
#define QSCALE 0.25f
#endif

// fp32 -> bf16 round-to-nearest-even
__device__ __forceinline__ u16 f2b(float f) {
    u32 u = __builtin_bit_cast(u32, f);
    u = (u + 0x7fffu + ((u >> 16) & 1u)) >> 16;
    return (u16)u;
}
// bf16 -> fp32
__device__ __forceinline__ float b2f(u16 u) {
    return __builtin_bit_cast(float, (u32)u << 16);
}
// pack two fp32 into 2 bf16 (round-half-away on magnitude): lo=a, hi=b.
__device__ __forceinline__ u32 pkbf(float a, float b) {
    u32 ua = __builtin_bit_cast(u32, a) + 0x8000u;
    u32 ub = __builtin_bit_cast(u32, b) + 0x8000u;
    return __builtin_amdgcn_perm(ub, ua, 0x07060302);  // {ua.hi16, ub.hi16}
}

// PyTorch-style sinusoidal PE
__device__ __forceinline__ float pe_val(int pos, int d) {
    int j = d >> 1;
    float div = expf((float)j * -0.14391156831212787f);
    float ang = (float)pos * div;
    return (d & 1) ? cosf(ang) : sinf(ang);
}

__global__ void embed_kernel(const int* __restrict__ src, const float* __restrict__ emb,
                             u16* __restrict__ Sb) {
    int idx = blockIdx.x * 256 + threadIdx.x;
    int d = idx & 127;
    int n = idx >> 7;
    int i = n & 63;
    int tok = src[n];
    Sb[idx] = f2b(emb[tok * 128 + d] * 11.313708498984761f + pe_val(i, d));
}

__global__ void addpe_kernel(const float* __restrict__ tgt, u16* __restrict__ Tb) {
    int idx = blockIdx.x * 256 + threadIdx.x;
    int d = idx & 127;
    int n = idx >> 7;
    int i = n & 1023;
    Tb[idx] = f2b(tgt[idx] + pe_val(i, d));
}

struct CvtJobs { const float* src[10]; u16* dst[10]; int n[10]; };
__global__ void cvt_kernel(CvtJobs jb) {
    int e = blockIdx.y;
    int i = blockIdx.x * 256 + threadIdx.x;
    if (i < jb.n[e]) jb.dst[e][i] = f2b(jb.src[e][i]);
}

// ---------------------------------------------------------------------------
// LDS-free MFMA GEMM: C[m,n] = sum_k A[m,k]*W[n,k] + bias[n].
// Optional qscale on cols < qcols; optional RELU; optional fused V-transpose
// (n-block at vcol0 is written to vt[((b*8+h)*16+n)*skv + tok] instead of C).
template <int AI, int BJ, int WM, int WN, int RELU>
__global__ __launch_bounds__(64 * WM * WN) void gemm_direct(
    const u16* __restrict__ A, const u16* __restrict__ W,
    const float* __restrict__ bias, u16* __restrict__ C,
    int M, int N, int K, float qscale, int qcols,
    u16* __restrict__ vt, int vcol0, int sshift, int smask, int skv) {
    int tid = threadIdx.x;
    int lane = tid & 63, w = tid >> 6;
    int quad = lane >> 4, l15 = lane & 15;
    int wmi = w % WM, wni = w / WM;
    int m0 = blockIdx.y * (16 * AI * WM), n0 = blockIdx.x * (16 * BJ * WN);
    int mb = m0 + wmi * 16 * AI, nb = n0 + wni * 16 * BJ;

    const u16* Ab = A + (size_t)(mb + l15) * K + quad * 8;
    const u16* Wb = W + (size_t)(nb + l15) * K + quad * 8;

    f32x4 acc[AI][BJ];
#pragma unroll
    for (int i = 0; i < AI; i++)
#pragma unroll
        for (int j = 0; j < BJ; j++)
#pragma unroll
            for (int r = 0; r < 4; r++) acc[i][j][r] = 0.f;

#pragma unroll 2
    for (int k0 = 0; k0 < K; k0 += 32) {
        s8b af[AI], bf[BJ];
#pragma unroll
        for (int i = 0; i < AI; i++) af[i] = *(const s8b*)(Ab + (size_t)16 * i * K + k0);
#pragma unroll
        for (int j = 0; j < BJ; j++) bf[j] = *(const s8b*)(Wb + (size_t)16 * j * K + k0);
#pragma unroll
        for (int i = 0; i < AI; i++)
#pragma unroll
            for (int j = 0; j < BJ; j++)
                acc[i][j] = __builtin_amdgcn_mfma_f32_16x16x32_bf16(af[i], bf[j], acc[i][j], 0, 0, 0);
    }

    if (vt && n0 == vcol0) {
#pragma unroll
        for (int j = 0; j < BJ; j++) {
            int lc = wni * 16 * BJ + 16 * j + l15;
            int h = lc >> 4, n = lc & 15;
            float bv = bias[vcol0 + lc];
#pragma unroll
            for (int i = 0; i < AI; i++) {
                int row = mb + 16 * i + quad * 4;
                int b = row >> sshift, tok = row & smask;
                u32 lo = pkbf(acc[i][j][0] + bv, acc[i][j][1] + bv);
                u32 hi = pkbf(acc[i][j][2] + bv, acc[i][j][3] + bv);
                u32* p = (u32*)(vt + ((size_t)((b * 8 + h) * 16 + n)) * skv + tok);
                p[0] = lo; p[1] = hi;
            }
        }
        return;
    }
#pragma unroll
    for (int j = 0; j < BJ; j++) {
        int col = nb + 16 * j + l15;
        float bv = bias[col];
        float sc = (col < qcols) ? qscale : 1.f;
#pragma unroll
        for (int i = 0; i < AI; i++) {
            int rbase = mb + 16 * i + quad * 4;
#pragma unroll
            for (int r = 0; r < 4; r++) {
                float v = (acc[i][j][r] + bv) * sc;
                if (RELU) v = fmaxf(v, 0.f);
                C[(size_t)(rbase + r) * N + col] = f2b(v);
            }
        }
    }
}

// ---------------------------------------------------------------------------
// LDS-free GEMM (N=128) fused with residual-add + LayerNorm.
// Residual X is bf16; output bf16 only (bf16 residual stream).
template <int AI, int BJ, int WM, int WN>
__global__ __launch_bounds__(64 * WM * WN) void gemm_ln_t(
    const u16* __restrict__ A, const u16* __restrict__ W,
    const float* __restrict__ bias, const u16* __restrict__ X,
    const float* __restrict__ g, const float* __restrict__ bta,
    u16* __restrict__ Yb, int M, int K) {
    __shared__ float redS[16 * AI * WM][WN], redQ[16 * AI * WM][WN];
    int tid = threadIdx.x;
    int lane = tid & 63, w = tid >> 6;
    int quad = lane >> 4, l15 = lane & 15;
    int wmi = w % WM, wni = w / WM;
    int m0 = blockIdx.x * (16 * AI * WM);
    int mb = m0 + wmi * 16 * AI, nb = wni * 16 * BJ;

    const u16* Ab = A + (size_t)(mb + l15) * K + quad * 8;
    const u16* Wb = W + (size_t)(nb + l15) * K + quad * 8;

    f32x4 acc[AI][BJ];
#pragma unroll
    for (int i = 0; i < AI; i++)
#pragma unroll
        for (int j = 0; j < BJ; j++)
#pragma unroll
            for (int r = 0; r < 4; r++) acc[i][j][r] = 0.f;

#pragma unroll 2
    for (int k0 = 0; k0 < K; k0 += 32) {
        s8b af[AI], bf[BJ];
#pragma unroll
        for (int i = 0; i < AI; i++) af[i] = *(const s8b*)(Ab + (size_t)16 * i * K + k0);
#pragma unroll
        for (int j = 0; j < BJ; j++) bf[j] = *(const s8b*)(Wb + (size_t)16 * j * K + k0);
#pragma unroll
        for (int i = 0; i < AI; i++)
#pragma unroll
            for (int j = 0; j < BJ; j++)
                acc[i][j] = __builtin_amdgcn_mfma_f32_16x16x32_bf16(af[i], bf[j], acc[i][j], 0, 0, 0);
    }

#pragma unroll
    for (int i = 0; i < AI; i++)
#pragma unroll
        for (int r = 0; r < 4; r++) {
            int row = mb + 16 * i + quad * 4 + r;
            float s = 0.f, q = 0.f;
#pragma unroll
            for (int j = 0; j < BJ; j++) {
                int col = nb + 16 * j + l15;
                float x = acc[i][j][r] + bias[col] + b2f(X[(size_t)row * 128 + col]);
                acc[i][j][r] = x;
                s += x; q += x * x;
            }
#pragma unroll
            for (int off = 1; off < 16; off <<= 1) {
                s += __shfl_xor(s, off);
                q += __shfl_xor(q, off);
            }
            if (l15 == 0) {
                int lrow = wmi * 16 * AI + 16 * i + quad * 4 + r;
                redS[lrow][wni] = s;
                redQ[lrow][wni] = q;
            }
        }
    __syncthreads();
#pragma unroll
    for (int i = 0; i < AI; i++)
#pragma unroll
        for (int r = 0; r < 4; r++) {
            int lrow = wmi * 16 * AI + 16 * i + quad * 4 + r;
            int row = m0 + lrow;
            float S2 = 0.f, Q2 = 0.f;
#pragma unroll
            for (int u = 0; u < WN; u++) { S2 += redS[lrow][u]; Q2 += redQ[lrow][u]; }
            float mean = S2 * (1.f / 128.f);
            float var = Q2 * (1.f / 128.f) - mean * mean;
            float rstd = rsqrtf(var + 1e-5f);
#pragma unroll
            for (int j = 0; j < BJ; j++) {
                int col = nb + 16 * j + l15;
                float y = (acc[i][j][r] - mean) * rstd * g[col] + bta[col];
                Yb[(size_t)row * 128 + col] = f2b(y);
            }
        }
}

// ---------------------------------------------------------------------------
// attn4: MFMA flash attention, zero LDS. Q pre-scaled by QSCALE.
// QK^T: S^T = mfma_32x32x16(K-frag, Q-frag) where lane m loads key sigma(m)
// (sigma = swap bits 2<->3). The resulting C-layout puts, in each lane's regs
// r0..7 / r8..15, exactly the 8+8 contiguous keys its PV B-fragment needs:
//   key(e_r) = j0 + (r<8 ? half*8+r : 16+half*8+(r-8)).
// PV: O^T = mfma_32x32x16(V^T A-frag from vt, packed P) accumulated over two
// 16-key chunks. Row-sums: per-lane VALU adds + one shfl_xor(32) at the end.
// Grid = nqc*256 with bh = bid&255 so same-(b,h) blocks share an XCD (K reuse).
template <int WAVES>
__global__ __launch_bounds__(WAVES * 64) void attn4(
    const u16* __restrict__ Qb, int qstride,
    const u16* __restrict__ Kb, int kstride, int koff,
    const u16* __restrict__ VT,
    u16* __restrict__ O, int SQ, int SKV) {
    int tid = threadIdx.x;
    int lane = tid & 63, w = tid >> 6;
    int l31 = lane & 31, half = lane >> 5;
    int bid = blockIdx.x;
    int bh = bid & 255;
    int qc = bid >> 8;
    int h = bh & 7, b = bh >> 3;
    int q0 = qc * (WAVES * 32) + w * 32;

    int ksw = (l31 & 19) | ((l31 & 4) << 1) | ((l31 & 8) >> 1);  // swap bits 2,3

    const u16* qp = Qb + (size_t)(b * SQ + q0 + l31) * qstride + h * 16 + half * 8;
    s8b qf = *(const s8b*)qp;
    const u16* kp = Kb + (size_t)(b * SKV + ksw) * kstride + koff + h * 16 + half * 8;
    size_t kadv = (size_t)32 * kstride;
    const u16* va = VT + (size_t)(bh * 16 + l31) * SKV + half * 8;

    f32x16 Oa;
#pragma unroll
    for (int r = 0; r < 16; r++) Oa[r] = 0.f;
    float lsum = 0.f;

#pragma unroll 2
    for (int j0 = 0; j0 < SKV; j0 += 32) {
        s8b kf = *(const s8b*)kp;
        kp += kadv;
        s8b v1 = *(const s8b*)(va + j0);
        s8b v2 = *(const s8b*)(va + j0 + 16);
        f32x16 S;
#pragma unroll
        for (int r = 0; r < 16; r++) S[r] = 0.f;
        S = __builtin_amdgcn_mfma_f32_32x32x16_bf16(kf, qf, S, 0, 0, 0);
        float e[16];
#pragma unroll
        for (int r = 0; r < 16; r++) { e[r] = EXPS(S[r]); lsum += e[r]; }
        u32x4 p1, p2;
        p1[0] = pkbf(e[0], e[1]);  p1[1] = pkbf(e[2], e[3]);
        p1[2] = pkbf(e[4], e[5]);  p1[3] = pkbf(e[6], e[7]);
        p2[0] = pkbf(e[8], e[9]);  p2[1] = pkbf(e[10], e[11]);
        p2[2] = pkbf(e[12], e[13]); p2[3] = pkbf(e[14], e[15]);
        s8b B1 = __builtin_bit_cast(s8b, p1);
        s8b B2 = __builtin_bit_cast(s8b, p2);
        Oa = __builtin_amdgcn_mfma_f32_32x32x16_bf16(v1, B1, Oa, 0, 0, 0);
        Oa = __builtin_amdgcn_mfma_f32_32x32x16_bf16(v2, B2, Oa, 0, 0, 0);
    }
    lsum += __shfl_xor(lsum, 32);
    float inv = 1.f / lsum;
    // valid O^T rows r0..7: dim = (r&3) + 8*(r>>2) + 4*half; col = q = l31
    int q = b * SQ + q0 + l31;
    u16* op = O + (size_t)q * 128 + h * 16 + 4 * half;
    ((u32*)op)[0] = pkbf(Oa[0] * inv, Oa[1] * inv);
    ((u32*)op)[1] = pkbf(Oa[2] * inv, Oa[3] * inv);
    ((u32*)(op + 8))[0] = pkbf(Oa[4] * inv, Oa[5] * inv);
    ((u32*)(op + 8))[1] = pkbf(Oa[6] * inv, Oa[7] * inv);
}

// Standalone LN over 128 cols, bf16 input; optional fp32 + bf16 outputs.
__global__ void ln_bf(const u16* __restrict__ X,
                      const float* __restrict__ g, const float* __restrict__ bta,
                      float* __restrict__ Yf, u16* __restrict__ Yb) {
    int r = blockIdx.x;
    int lane = threadIdx.x;
    size_t base = (size_t)r * 128;
    float x0 = b2f(X[base + lane]), x1 = b2f(X[base + lane + 64]);
    float s = x0 + x1;
    for (int off = 32; off; off >>= 1) s += __shfl_xor(s, off);
    float mean = s * (1.f / 128.f);
    float d0 = x0 - mean, d1 = x1 - mean;
    float vs = d0 * d0 + d1 * d1;
    for (int off = 32; off; off >>= 1) vs += __shfl_xor(vs, off);
    float rstd = rsqrtf(vs * (1.f / 128.f) + 1e-5f);
    float y0 = d0 * rstd * g[lane] + bta[lane];
    float y1 = d1 * rstd * g[lane + 64] + bta[lane + 64];
    if (Yf) { Yf[base + lane] = y0; Yf[base + lane + 64] = y1; }
    if (Yb) { Yb[base + lane] = f2b(y0); Yb[base + lane + 64] = f2b(y1); }
}

__global__ void fc_kernel(const float* __restrict__ X, const float* __restrict__ w,
                          const float* __restrict__ b, float* __restrict__ out) {
    int r = blockIdx.x;
    int lane = threadIdx.x;
    size_t base = (size_t)r * 128;
    float s = X[base + lane] * w[lane] + X[base + lane + 64] * w[lane + 64];
    for (int off = 32; off; off >>= 1) s += __shfl_xor(s, off);
    if (lane == 0) out[r] = s + b[0];
}

// ---- launch helpers: D = decoder tile (128x128), E = encoder tile (32x128) ----
static inline void gemmD(const u16* A, const u16* W, const float* bias, u16* C,
                         int M, int N, int K, hipStream_t st, int qcols = 0,
                         u16* vt = nullptr, int vcol0 = 0, int sshift = 0, int skv = 0) {
    hipLaunchKernelGGL((gemm_direct<4, 4, 2, 2, 0>), dim3(N / 128, M / 128), dim3(256), 0, st,
                       A, W, bias, C, M, N, K, QSCALE, qcols, vt, vcol0, sshift, (1 << sshift) - 1, skv);
}
static inline void gemmDr(const u16* A, const u16* W, const float* bias, u16* C,
                          int M, int N, int K, hipStream_t st) {
    hipLaunchKernelGGL((gemm_direct<4, 4, 2, 2, 1>), dim3(N / 128, M / 128), dim3(256), 0, st,
                       A, W, bias, C, M, N, K, 1.f, 0, (u16*)nullptr, 0, 0, 0, 0);
}
static inline void gemmE(const u16* A, const u16* W, const float* bias, u16* C,
                         int M, int N, int K, hipStream_t st, int qcols = 0,
                         u16* vt = nullptr, int vcol0 = 0, int sshift = 0, int skv = 0) {
    hipLaunchKernelGGL((gemm_direct<2, 2, 1, 4, 0>), dim3(N / 128, M / 32), dim3(256), 0, st,
                       A, W, bias, C, M, N, K, QSCALE, qcols, vt, vcol0, sshift, (1 << sshift) - 1, skv);
}
static inline void gemmEr(const u16* A, const u16* W, const float* bias, u16* C,
                          int M, int N, int K, hipStream_t st) {
    hipLaunchKernelGGL((gemm_direct<2, 2, 1, 4, 1>), dim3(N / 128, M / 32), dim3(256), 0, st,
                       A, W, bias, C, M, N, K, 1.f, 0, (u16*)nullptr, 0, 0, 0, 0);
}
static inline void gemmlnD(const u16* A, const u16* W, const float* bias,
                           const u16* X, const float* g, const float* bta,
                           u16* Yb, int M, int K, hipStream_t st) {
    hipLaunchKernelGGL((gemm_ln_t<4, 4, 2, 2>), dim3(M / 128), dim3(256), 0, st,
                       A, W, bias, X, g, bta, Yb, M, K);
}
static inline void gemmlnE(const u16* A, const u16* W, const float* bias,
                           const u16* X, const float* g, const float* bta,
                           u16* Yb, int M, int K, hipStream_t st) {
    hipLaunchKernelGGL((gemm_ln_t<2, 2, 1, 4>), dim3(M / 32), dim3(256), 0, st,
                       A, W, bias, X, g, bta, Yb, M, K);
}

extern "C" void kernel_launch(void* const* d_in, const int* in_sizes, int n_in,
                              void* d_out, int out_size, void* d_ws, size_t ws_size,
                              hipStream_t stream) {
    const int B = 32, SSRC = 64, STGT = 1024, D = 128, DFF_ = 512, LE = 6, LD = 6;

    const int*   src = (const int*)d_in[0];
    const float* tgt = (const float*)d_in[1];
    const float* emb = (const float*)d_in[2];
    const float* enc_qkv_w = (const float*)d_in[3];
    const float* enc_qkv_b = (const float*)d_in[4];
    const float* enc_out_w = (const float*)d_in[5];
    const float* enc_out_b = (const float*)d_in[6];
    const float* enc_ln1_g = (const float*)d_in[7];
    const float* enc_ln1_b = (const float*)d_in[8];
    const float* enc_ff1_w = (const float*)d_in[9];
    const float* enc_ff1_b = (const float*)d_in[10];
    const float* enc_ff2_w = (const float*)d_in[11];
    const float* enc_ff2_b = (const float*)d_in[12];
    const float* enc_ln2_g = (const float*)d_in[13];
    const float* enc_ln2_b = (const float*)d_in[14];
    const float* enc_norm_g = (const float*)d_in[15];
    const float* enc_norm_b = (const float*)d_in[16];
    const float* dec_sa_qkv_w = (const float*)d_in[17];
    const float* dec_sa_qkv_b = (const float*)d_in[18];
    const float* dec_sa_out_w = (const float*)d_in[19];
    const float* dec_sa_out_b = (const float*)d_in[20];
    const float* dec_ln1_g = (const float*)d_in[21];
    const float* dec_ln1_b = (const float*)d_in[22];
    const float* dec_ca_qkv_w = (const float*)d_in[23];
    const float* dec_ca_qkv_b = (const float*)d_in[24];
    const float* dec_ca_out_w = (const float*)d_in[25];
    const float* dec_ca_out_b = (const float*)d_in[26];
    const float* dec_ln2_g = (const float*)d_in[27];
    const float* dec_ln2_b = (const float*)d_in[28];
    const float* dec_ff1_w = (const float*)d_in[29];
    const float* dec_ff1_b = (const float*)d_in[30];
    const float* dec_ff2_w = (const float*)d_in[31];
    const float* dec_ff2_b = (const float*)d_in[32];
    const float* dec_ln3_g = (const float*)d_in[33];
    const float* dec_ln3_b = (const float*)d_in[34];
    const float* dec_norm_g = (const float*)d_in[35];
    const float* dec_norm_b = (const float*)d_in[36];
    const float* fc_w = (const float*)d_in[37];
    const float* fc_b = (const float*)d_in[38];

    const int NT = B * STGT;   // 32768
    const int NS = B * SSRC;   // 2048

    // ---- workspace: bf16 activations only; fp32 scratch aliases qkv ----
    u16* t_bf    = (u16*)d_ws;                   // 32768*128
    u16* s_bf    = t_bf + (size_t)NT * D;        // 2048*128
    u16* mem_bf  = s_bf + (size_t)NS * D;        // 2048*128
    u16* qkv_bf  = mem_bf + (size_t)NS * D;      // 32768*512
    u16* attno_bf = qkv_bf + (size_t)NT * DFF_;  // 32768*128
    u16* ckv_bf  = attno_bf + (size_t)NT * D;    // 2048*256
    u16* vt      = ckv_bf + (size_t)NS * 2 * D;  // B*NH*16*1024 + pad 16*1024
    u16* wa      = vt + (size_t)B * NH * 16 * STGT + 16 * STGT;

    u16* w_enc_qkv = wa;                          int n_enc_qkv = LE * 3 * D * D;
    u16* w_enc_out = w_enc_qkv + n_enc_qkv;       int n_enc_out = LE * D * D;
    u16* w_enc_ff1 = w_enc_out + n_enc_out;       int n_enc_ff1 = LE * DFF_ * D;
    u16* w_enc_ff2 = w_enc_ff1 + n_enc_ff1;       int n_enc_ff2 = LE * D * DFF_;
    u16* w_sa_qkv  = w_enc_ff2 + n_enc_ff2;       int n_sa_qkv = LD * 3 * D * D;
    u16* w_sa_out  = w_sa_qkv + n_sa_qkv;         int n_sa_out = LD * D * D;
    u16* w_ca_qkv  = w_sa_out + n_sa_out;         int n_ca_qkv = LD * 3 * D * D;
    u16* w_ca_out  = w_ca_qkv + n_ca_qkv;         int n_ca_out = LD * D * D;
    u16* w_ff1     = w_ca_out + n_ca_out;         int n_ff1 = LD * DFF_ * D;
    u16* w_ff2     = w_ff1 + n_ff1;               int n_ff2 = LD * D * DFF_;

    float* scf = (float*)qkv_bf;  // final-LN fp32 scratch (qkv dead by then)

    CvtJobs jb;
    jb.src[0] = enc_qkv_w;    jb.dst[0] = w_enc_qkv; jb.n[0] = n_enc_qkv;
    jb.src[1] = enc_out_w;    jb.dst[1] = w_enc_out; jb.n[1] = n_enc_out;
    jb.src[2] = enc_ff1_w;    jb.dst[2] = w_enc_ff1; jb.n[2] = n_enc_ff1;
    jb.src[3] = enc_ff2_w;    jb.dst[3] = w_enc_ff2; jb.n[3] = n_enc_ff2;
    jb.src[4] = dec_sa_qkv_w; jb.dst[4] = w_sa_qkv;  jb.n[4] = n_sa_qkv;
    jb.src[5] = dec_sa_out_w; jb.dst[5] = w_sa_out;  jb.n[5] = n_sa_out;
    jb.src[6] = dec_ca_qkv_w; jb.dst[6] = w_ca_qkv;  jb.n[6] = n_ca_qkv;
    jb.src[7] = dec_ca_out_w; jb.dst[7] = w_ca_out;  jb.n[7] = n_ca_out;
    jb.src[8] = dec_ff1_w;    jb.dst[8] = w_ff1;     jb.n[8] = n_ff1;
    jb.src[9] = dec_ff2_w;    jb.dst[9] = w_ff2;     jb.n[9] = n_ff2;
    int maxn = n_enc_ff1;
    hipLaunchKernelGGL(cvt_kernel, dim3((maxn + 255) / 256, 10), dim3(256), 0, stream, jb);

    // ---------------- Encoder ----------------
    hipLaunchKernelGGL(embed_kernel, dim3(NS * D / 256), dim3(256), 0, stream, src, emb, s_bf);

    for (int i = 0; i < LE; i++) {
        gemmE(s_bf, w_enc_qkv + (size_t)i * 3 * D * D, enc_qkv_b + (size_t)i * 3 * D,
              qkv_bf, NS, 3 * D, D, stream, 128, vt, 256, 6, SSRC);  // Q scaled, V->vt
        hipLaunchKernelGGL((attn4<2>), dim3(256), dim3(128), 0, stream,
                           qkv_bf, 3 * D, qkv_bf, 3 * D, D, vt, attno_bf, SSRC, SSRC);
        gemmlnE(attno_bf, w_enc_out + (size_t)i * D * D, enc_out_b + (size_t)i * D,
                s_bf, enc_ln1_g + (size_t)i * D, enc_ln1_b + (size_t)i * D, s_bf, NS, D, stream);
        gemmEr(s_bf, w_enc_ff1 + (size_t)i * DFF_ * D, enc_ff1_b + (size_t)i * DFF_,
               qkv_bf, NS, DFF_, D, stream);
        gemmlnE(qkv_bf, w_enc_ff2 + (size_t)i * D * DFF_, enc_ff2_b + (size_t)i * D,
                s_bf, enc_ln2_g + (size_t)i * D, enc_ln2_b + (size_t)i * D, s_bf, NS, DFF_, stream);
    }
    hipLaunchKernelGGL(ln_bf, dim3(NS), dim3(64), 0, stream,
                       s_bf, enc_norm_g, enc_norm_b, (float*)nullptr, mem_bf);

    // ---------------- Decoder ----------------
    hipLaunchKernelGGL(addpe_kernel, dim3(NT * D / 256), dim3(256), 0, stream, tgt, t_bf);

    for (int i = 0; i < LD; i++) {
        // self-attention
        gemmD(t_bf, w_sa_qkv + (size_t)i * 3 * D * D, dec_sa_qkv_b + (size_t)i * 3 * D,
              qkv_bf, NT, 3 * D, D, stream, 128, vt, 256, 10, STGT);  // Q scaled, V->vt
        hipLaunchKernelGGL((attn4<4>), dim3(8 * 256), dim3(256), 0, stream,
                           qkv_bf, 3 * D, qkv_bf, 3 * D, D, vt, attno_bf, STGT, STGT);
        gemmlnD(attno_bf, w_sa_out + (size_t)i * D * D, dec_sa_out_b + (size_t)i * D,
                t_bf, dec_ln1_g + (size_t)i * D, dec_ln1_b + (size_t)i * D, t_bf, NT, D, stream);

        // cross-attention
        gemmD(t_bf, w_ca_qkv + (size_t)i * 3 * D * D, dec_ca_qkv_b + (size_t)i * 3 * D,
              qkv_bf, NT, D, D, stream, 128);  // Q only, pre-scaled
        gemmE(mem_bf, w_ca_qkv + (size_t)i * 3 * D * D + (size_t)D * D,
              dec_ca_qkv_b + (size_t)i * 3 * D + D, ckv_bf, NS, 2 * D, D, stream,
              0, vt, 128, 6, SSRC);  // K->ckv, V->vt
        hipLaunchKernelGGL((attn4<4>), dim3(8 * 256), dim3(256), 0, stream,
                           qkv_bf, D, ckv_bf, 2 * D, 0, vt, attno_bf, STGT, SSRC);
        gemmlnD(attno_bf, w_ca_out + (size_t)i * D * D, dec_ca_out_b + (size_t)i * D,
                t_bf, dec_ln2_g + (size_t)i * D, dec_ln2_b + (size_t)i * D, t_bf, NT, D, stream);

        // FFN
        gemmDr(t_bf, w_ff1 + (size_t)i * DFF_ * D, dec_ff1_b + (size_t)i * DFF_,
               qkv_bf, NT, DFF_, D, stream);
        gemmlnD(qkv_bf, w_ff2 + (size_t)i * D * DFF_, dec_ff2_b + (size_t)i * D,
                t_bf, dec_ln3_g + (size_t)i * D, dec_ln3_b + (size_t)i * D, t_bf, NT, DFF_, stream);
    }

    hipLaunchKernelGGL(ln_bf, dim3(NT), dim3(64), 0, stream,
                       t_bf, dec_norm_g, dec_norm_b, scf, (u16*)nullptr);
    hipLaunchKernelGGL(fc_kernel, dim3(NT), dim3(64), 0, stream,
                       scf, fc_w, fc_b, (float*)d_out);
}

// Round 9
// 1451.208 us; speedup vs baseline: 1.3238x; 1.3238x over previous
//
#include <hip/hip_runtime.h>
#include <hip/hip_bf16.h>
#include <stdint.h>

#define NH 8

typedef uint16_t u16;
typedef uint32_t u32;
typedef __attribute__((ext_vector_type(2))) u32 u32x2;
typedef __attribute__((ext_vector_type(8))) short s8b;    // 8 bf16 (4 VGPR)
typedef __attribute__((ext_vector_type(4))) float f32x4;
typedef __attribute__((ext_vector_type(16))) float f32x16;

#if __has_builtin(__builtin_amdgcn_exp2f)
#define EXPS(x) __builtin_amdgcn_exp2f(x)
#define QSCALE 0.36067376022224085f   // 0.25 * log2(e)
#else
#define EXPS(x) __expf(x)
#define QSCALE 0.25f
#endif

// fp32 -> bf16 round-to-nearest-even
__device__ __forceinline__ u16 f2b(float f) {
    u32 u = __builtin_bit_cast(u32, f);
    u = (u + 0x7fffu + ((u >> 16) & 1u)) >> 16;
    return (u16)u;
}
// bf16 -> fp32
__device__ __forceinline__ float b2f(u16 u) {
    return __builtin_bit_cast(float, (u32)u << 16);
}
// pack two fp32 into 2 bf16 (round-half-away): lo=a, hi=b.
__device__ __forceinline__ u32 pkbf(float a, float b) {
    u32 ua = __builtin_bit_cast(u32, a) + 0x8000u;
    u32 ub = __builtin_bit_cast(u32, b) + 0x8000u;
    return __builtin_amdgcn_perm(ub, ua, 0x07060302);  // {ua.hi16, ub.hi16}
}

// PyTorch-style sinusoidal PE
__device__ __forceinline__ float pe_val(int pos, int d) {
    int j = d >> 1;
    float div = expf((float)j * -0.14391156831212787f);
    float ang = (float)pos * div;
    return (d & 1) ? cosf(ang) : sinf(ang);
}

__global__ void embed_kernel(const int* __restrict__ src, const float* __restrict__ emb,
                             u16* __restrict__ Sb) {
    int idx = blockIdx.x * 256 + threadIdx.x;
    int d = idx & 127;
    int n = idx >> 7;
    int i = n & 63;
    int tok = src[n];
    Sb[idx] = f2b(emb[tok * 128 + d] * 11.313708498984761f + pe_val(i, d));
}

__global__ void addpe_kernel(const float* __restrict__ tgt, u16* __restrict__ Tb) {
    int idx = blockIdx.x * 256 + threadIdx.x;
    int d = idx & 127;
    int n = idx >> 7;
    int i = n & 1023;
    Tb[idx] = f2b(tgt[idx] + pe_val(i, d));
}

struct CvtJobs { const float* src[10]; u16* dst[10]; int n[10]; };
__global__ void cvt_kernel(CvtJobs jb) {
    int e = blockIdx.y;
    int i = blockIdx.x * 256 + threadIdx.x;
    if (i < jb.n[e]) jb.dst[e][i] = f2b(jb.src[e][i]);
}

// ---------------------------------------------------------------------------
// LDS-staged MFMA GEMM (round-6 structure): C[m,n] = sum_k A[m,k]*W[n,k]+bias.
// 128x128 tile, 4 waves x 64x64. Optional qscale on cols<qcols; optional RELU;
// optional fused V-transpose: n-block at vcol0 goes to
// vt[((b*8+h)*16+n)*skv + tok] (8B packed stores) instead of C.
template <int RELU>
__global__ __launch_bounds__(256) void gemm_mfma(
    const u16* __restrict__ A, const u16* __restrict__ W,
    const float* __restrict__ bias, u16* __restrict__ C,
    int M, int N, int K, float qscale, int qcols,
    u16* __restrict__ vt, int vcol0, int sshift, int smask, int skv) {
    __shared__ __align__(16) u16 As[128 * 56];
    __shared__ __align__(16) u16 Bs[128 * 56];
    int tid = threadIdx.x;
    int lane = tid & 63, w = tid >> 6;
    int quad = lane >> 4, l15 = lane & 15;
    int m0 = blockIdx.y * 128, n0 = blockIdx.x * 128;
    int wm = (w & 1) * 64, wn = (w >> 1) * 64;
    int srow = tid >> 1, skof = (tid & 1) * 16;

    f32x4 acc[4][4];
#pragma unroll
    for (int i = 0; i < 4; i++)
#pragma unroll
        for (int j = 0; j < 4; j++)
#pragma unroll
            for (int r = 0; r < 4; r++) acc[i][j][r] = 0.f;

    for (int k0 = 0; k0 < K; k0 += 32) {
        const u16* ga = A + (size_t)(m0 + srow) * K + k0 + skof;
        const u16* gw = W + (size_t)(n0 + srow) * K + k0 + skof;
        s8b a0 = *(const s8b*)ga, a1 = *(const s8b*)(ga + 8);
        s8b w0 = *(const s8b*)gw, w1 = *(const s8b*)(gw + 8);
        __syncthreads();
        *(s8b*)(As + srow * 56 + skof) = a0;
        *(s8b*)(As + srow * 56 + skof + 8) = a1;
        *(s8b*)(Bs + srow * 56 + skof) = w0;
        *(s8b*)(Bs + srow * 56 + skof + 8) = w1;
        __syncthreads();
        s8b af[4], bfr[4];
#pragma unroll
        for (int i = 0; i < 4; i++) af[i] = *(const s8b*)(As + (wm + 16 * i + l15) * 56 + quad * 8);
#pragma unroll
        for (int j = 0; j < 4; j++) bfr[j] = *(const s8b*)(Bs + (wn + 16 * j + l15) * 56 + quad * 8);
#pragma unroll
        for (int i = 0; i < 4; i++)
#pragma unroll
            for (int j = 0; j < 4; j++)
                acc[i][j] = __builtin_amdgcn_mfma_f32_16x16x32_bf16(af[i], bfr[j], acc[i][j], 0, 0, 0);
    }

    if (vt && n0 == vcol0) {
        // V-block: write transposed to vt. C rows quad*4..+3 = consecutive tokens.
#pragma unroll
        for (int j = 0; j < 4; j++) {
            int lc = wn + 16 * j + l15;
            int h = lc >> 4, n = lc & 15;
            float bv = bias[vcol0 + lc];
#pragma unroll
            for (int i = 0; i < 4; i++) {
                int row = m0 + wm + 16 * i + quad * 4;
                int b = row >> sshift, tok = row & smask;
                u32 lo = pkbf(acc[i][j][0] + bv, acc[i][j][1] + bv);
                u32 hi = pkbf(acc[i][j][2] + bv, acc[i][j][3] + bv);
                u32* p = (u32*)(vt + ((size_t)((b * 8 + h) * 16 + n)) * skv + tok);
                p[0] = lo; p[1] = hi;
            }
        }
        return;
    }
#pragma unroll
    for (int j = 0; j < 4; j++) {
        int col = n0 + wn + 16 * j + l15;
        float bv = bias[col];
        float sc = (col < qcols) ? qscale : 1.f;
#pragma unroll
        for (int i = 0; i < 4; i++) {
            int rbase = m0 + wm + 16 * i + quad * 4;
#pragma unroll
            for (int r = 0; r < 4; r++) {
                float v = (acc[i][j][r] + bv) * sc;
                if (RELU) v = fmaxf(v, 0.f);
                C[(size_t)(rbase + r) * N + col] = f2b(v);
            }
        }
    }
}

// ---------------------------------------------------------------------------
// LDS-staged GEMM (N=128) fused with residual-add + LayerNorm. bf16 residual
// stream: X and output are bf16.
__global__ __launch_bounds__(256) void gemm_ln(
    const u16* __restrict__ A, const u16* __restrict__ W,
    const float* __restrict__ bias, const u16* __restrict__ X,
    const float* __restrict__ g, const float* __restrict__ bta,
    u16* __restrict__ Yb, int M, int K) {
    __shared__ __align__(16) u16 As[128 * 56];
    __shared__ __align__(16) u16 Bs[128 * 56];
    __shared__ float redS[128][2], redQ[128][2];
    int tid = threadIdx.x;
    int lane = tid & 63, w = tid >> 6;
    int quad = lane >> 4, l15 = lane & 15;
    int m0 = blockIdx.x * 128;
    int wm = (w & 1) * 64, wn = (w >> 1) * 64;
    int srow = tid >> 1, skof = (tid & 1) * 16;

    f32x4 acc[4][4];
#pragma unroll
    for (int i = 0; i < 4; i++)
#pragma unroll
        for (int j = 0; j < 4; j++)
#pragma unroll
            for (int r = 0; r < 4; r++) acc[i][j][r] = 0.f;

    for (int k0 = 0; k0 < K; k0 += 32) {
        const u16* ga = A + (size_t)(m0 + srow) * K + k0 + skof;
        const u16* gw = W + (size_t)srow * K + k0 + skof;
        s8b a0 = *(const s8b*)ga, a1 = *(const s8b*)(ga + 8);
        s8b w0 = *(const s8b*)gw, w1 = *(const s8b*)(gw + 8);
        __syncthreads();
        *(s8b*)(As + srow * 56 + skof) = a0;
        *(s8b*)(As + srow * 56 + skof + 8) = a1;
        *(s8b*)(Bs + srow * 56 + skof) = w0;
        *(s8b*)(Bs + srow * 56 + skof + 8) = w1;
        __syncthreads();
        s8b af[4], bfr[4];
#pragma unroll
        for (int i = 0; i < 4; i++) af[i] = *(const s8b*)(As + (wm + 16 * i + l15) * 56 + quad * 8);
#pragma unroll
        for (int j = 0; j < 4; j++) bfr[j] = *(const s8b*)(Bs + (wn + 16 * j + l15) * 56 + quad * 8);
#pragma unroll
        for (int i = 0; i < 4; i++)
#pragma unroll
            for (int j = 0; j < 4; j++)
                acc[i][j] = __builtin_amdgcn_mfma_f32_16x16x32_bf16(af[i], bfr[j], acc[i][j], 0, 0, 0);
    }

    float s_[4][4], q_[4][4];
#pragma unroll
    for (int i = 0; i < 4; i++)
#pragma unroll
        for (int r = 0; r < 4; r++) {
            int row = m0 + wm + 16 * i + quad * 4 + r;
            float s = 0.f, q = 0.f;
#pragma unroll
            for (int j = 0; j < 4; j++) {
                int col = wn + 16 * j + l15;
                float x = acc[i][j][r] + bias[col] + b2f(X[(size_t)row * 128 + col]);
                acc[i][j][r] = x;
                s += x; q += x * x;
            }
#pragma unroll
            for (int off = 1; off < 16; off <<= 1) {
                s += __shfl_xor(s, off);
                q += __shfl_xor(q, off);
            }
            s_[i][r] = s; q_[i][r] = q;
        }
    if (l15 == 0) {
#pragma unroll
        for (int i = 0; i < 4; i++)
#pragma unroll
            for (int r = 0; r < 4; r++) {
                int lrow = wm + 16 * i + quad * 4 + r;
                redS[lrow][wn >> 6] = s_[i][r];
                redQ[lrow][wn >> 6] = q_[i][r];
            }
    }
    __syncthreads();
#pragma unroll
    for (int i = 0; i < 4; i++)
#pragma unroll
        for (int r = 0; r < 4; r++) {
            int lrow = wm + 16 * i + quad * 4 + r;
            int row = m0 + lrow;
            float S2 = redS[lrow][0] + redS[lrow][1];
            float Q2 = redQ[lrow][0] + redQ[lrow][1];
            float mean = S2 * (1.f / 128.f);
            float var = Q2 * (1.f / 128.f) - mean * mean;
            float rstd = rsqrtf(var + 1e-5f);
#pragma unroll
            for (int j = 0; j < 4; j++) {
                int col = wn + 16 * j + l15;
                float y = (acc[i][j][r] - mean) * rstd * g[col] + bta[col];
                Yb[(size_t)row * 128 + col] = f2b(y);
            }
        }
}

// MFMA flash attention v3 (round-6 proven structure; P-stores as ds_write_b64).
template <int WAVES>
__global__ __launch_bounds__(WAVES * 64) void attn3(
    const u16* __restrict__ Qb, int qstride,
    const u16* __restrict__ Kb, int kstride, int koff,
    const u16* __restrict__ VT,
    u16* __restrict__ O, int SQ, int SKV) {
    __shared__ __align__(16) u32 Ps[WAVES][32 * 20];
    int tid = threadIdx.x;
    int lane = tid & 63, w = tid >> 6;
    int quad = lane >> 4, l15 = lane & 15, l31 = lane & 31, half = lane >> 5;
    int nqc = SQ / (WAVES * 32);
    int bid = blockIdx.x;
    int qc = bid % nqc;
    int h = (bid / nqc) % NH;
    int b = bid / (nqc * NH);
    int q0 = qc * WAVES * 32 + w * 32;

    const u16* qp = Qb + (size_t)(b * SQ + q0 + l31) * qstride + h * 16 + half * 8;
    s8b qf = *(const s8b*)qp;
    s8b ones;
#pragma unroll
    for (int j = 0; j < 8; j++) ones[j] = (short)0x3F80;  // bf16 1.0

    const u16* vtb = VT + ((size_t)(b * NH + h) * 16 + l15) * SKV + quad * 8;
    const u16* kp = Kb + (size_t)(b * SKV + l31) * kstride + koff + h * 16 + half * 8;
    size_t kadv = (size_t)32 * kstride;

    f32x4 O0, O1, L0, L1;
#pragma unroll
    for (int r = 0; r < 4; r++) { O0[r] = 0.f; O1[r] = 0.f; L0[r] = 0.f; L1[r] = 0.f; }

    u32* pw = Ps[w];
#pragma unroll 2
    for (int j0 = 0; j0 < SKV; j0 += 32) {
        s8b kf = *(const s8b*)kp;
        kp += kadv;
        s8b vb = *(const s8b*)(vtb + j0);
        f32x16 S;
#pragma unroll
        for (int r = 0; r < 16; r++) S[r] = 0.f;
        S = __builtin_amdgcn_mfma_f32_32x32x16_bf16(kf, qf, S, 0, 0, 0);  // S^T
        // C-layout: col = q = lane&31; row = key = (r&3) + 8*(r>>2) + 4*half
#pragma unroll
        for (int g = 0; g < 4; g++) {
            float p0 = EXPS(S[4 * g + 0]);
            float p1 = EXPS(S[4 * g + 1]);
            float p2 = EXPS(S[4 * g + 2]);
            float p3 = EXPS(S[4 * g + 3]);
            u32x2 pk;
            pk[0] = pkbf(p0, p1);
            pk[1] = pkbf(p2, p3);
            *(u32x2*)(pw + l31 * 20 + 2 * half + 4 * g) = pk;  // ds_write_b64
        }
        __builtin_amdgcn_wave_barrier();  // wave-private LDS RAW ordering
        s8b pa0 = *(const s8b*)(pw + l15 * 20 + quad * 4);
        s8b pa1 = *(const s8b*)(pw + (16 + l15) * 20 + quad * 4);
        O0 = __builtin_amdgcn_mfma_f32_16x16x32_bf16(pa0, vb, O0, 0, 0, 0);
        O1 = __builtin_amdgcn_mfma_f32_16x16x32_bf16(pa1, vb, O1, 0, 0, 0);
        L0 = __builtin_amdgcn_mfma_f32_16x16x32_bf16(pa0, ones, L0, 0, 0, 0);
        L1 = __builtin_amdgcn_mfma_f32_16x16x32_bf16(pa1, ones, L1, 0, 0, 0);
    }
#pragma unroll
    for (int r = 0; r < 4; r++) {
        int q = b * SQ + q0 + quad * 4 + r;
        O[(size_t)q * 128 + h * 16 + l15] = f2b(O0[r] / L0[r]);
        O[(size_t)(q + 16) * 128 + h * 16 + l15] = f2b(O1[r] / L1[r]);
    }
}

// Standalone LN over 128 cols, bf16 input; optional fp32 + bf16 outputs.
__global__ void ln_bf(const u16* __restrict__ X,
                      const float* __restrict__ g, const float* __restrict__ bta,
                      float* __restrict__ Yf, u16* __restrict__ Yb) {
    int r = blockIdx.x;
    int lane = threadIdx.x;
    size_t base = (size_t)r * 128;
    float x0 = b2f(X[base + lane]), x1 = b2f(X[base + lane + 64]);
    float s = x0 + x1;
    for (int off = 32; off; off >>= 1) s += __shfl_xor(s, off);
    float mean = s * (1.f / 128.f);
    float d0 = x0 - mean, d1 = x1 - mean;
    float vs = d0 * d0 + d1 * d1;
    for (int off = 32; off; off >>= 1) vs += __shfl_xor(vs, off);
    float rstd = rsqrtf(vs * (1.f / 128.f) + 1e-5f);
    float y0 = d0 * rstd * g[lane] + bta[lane];
    float y1 = d1 * rstd * g[lane + 64] + bta[lane + 64];
    if (Yf) { Yf[base + lane] = y0; Yf[base + lane + 64] = y1; }
    if (Yb) { Yb[base + lane] = f2b(y0); Yb[base + lane + 64] = f2b(y1); }
}

__global__ void fc_kernel(const float* __restrict__ X, const float* __restrict__ w,
                          const float* __restrict__ b, float* __restrict__ out) {
    int r = blockIdx.x;
    int lane = threadIdx.x;
    size_t base = (size_t)r * 128;
    float s = X[base + lane] * w[lane] + X[base + lane + 64] * w[lane + 64];
    for (int off = 32; off; off >>= 1) s += __shfl_xor(s, off);
    if (lane == 0) out[r] = s + b[0];
}

// ---- launch helpers ----
static inline void gemm_b(const u16* A, const u16* W, const float* bias, u16* C,
                          int M, int N, int K, hipStream_t st, int qcols = 0,
                          u16* vt = nullptr, int vcol0 = 0, int sshift = 0, int skv = 0) {
    hipLaunchKernelGGL((gemm_mfma<0>), dim3(N / 128, M / 128), dim3(256), 0, st,
                       A, W, bias, C, M, N, K, QSCALE, qcols, vt, vcol0, sshift,
                       (1 << sshift) - 1, skv);
}
static inline void gemm_br(const u16* A, const u16* W, const float* bias, u16* C,
                           int M, int N, int K, hipStream_t st) {
    hipLaunchKernelGGL((gemm_mfma<1>), dim3(N / 128, M / 128), dim3(256), 0, st,
                       A, W, bias, C, M, N, K, 1.f, 0, (u16*)nullptr, 0, 0, 0, 0);
}
static inline void gemmln(const u16* A, const u16* W, const float* bias,
                          const u16* X, const float* g, const float* bta,
                          u16* Yb, int M, int K, hipStream_t st) {
    hipLaunchKernelGGL(gemm_ln, dim3(M / 128), dim3(256), 0, st,
                       A, W, bias, X, g, bta, Yb, M, K);
}

extern "C" void kernel_launch(void* const* d_in, const int* in_sizes, int n_in,
                              void* d_out, int out_size, void* d_ws, size_t ws_size,
                              hipStream_t stream) {
    const int B = 32, SSRC = 64, STGT = 1024, D = 128, DFF_ = 512, LE = 6, LD = 6;

    const int*   src = (const int*)d_in[0];
    const float* tgt = (const float*)d_in[1];
    const float* emb = (const float*)d_in[2];
    const float* enc_qkv_w = (const float*)d_in[3];
    const float* enc_qkv_b = (const float*)d_in[4];
    const float* enc_out_w = (const float*)d_in[5];
    const float* enc_out_b = (const float*)d_in[6];
    const float* enc_ln1_g = (const float*)d_in[7];
    const float* enc_ln1_b = (const float*)d_in[8];
    const float* enc_ff1_w = (const float*)d_in[9];
    const float* enc_ff1_b = (const float*)d_in[10];
    const float* enc_ff2_w = (const float*)d_in[11];
    const float* enc_ff2_b = (const float*)d_in[12];
    const float* enc_ln2_g = (const float*)d_in[13];
    const float* enc_ln2_b = (const float*)d_in[14];
    const float* enc_norm_g = (const float*)d_in[15];
    const float* enc_norm_b = (const float*)d_in[16];
    const float* dec_sa_qkv_w = (const float*)d_in[17];
    const float* dec_sa_qkv_b = (const float*)d_in[18];
    const float* dec_sa_out_w = (const float*)d_in[19];
    const float* dec_sa_out_b = (const float*)d_in[20];
    const float* dec_ln1_g = (const float*)d_in[21];
    const float* dec_ln1_b = (const float*)d_in[22];
    const float* dec_ca_qkv_w = (const float*)d_in[23];
    const float* dec_ca_qkv_b = (const float*)d_in[24];
    const float* dec_ca_out_w = (const float*)d_in[25];
    const float* dec_ca_out_b = (const float*)d_in[26];
    const float* dec_ln2_g = (const float*)d_in[27];
    const float* dec_ln2_b = (const float*)d_in[28];
    const float* dec_ff1_w = (const float*)d_in[29];
    const float* dec_ff1_b = (const float*)d_in[30];
    const float* dec_ff2_w = (const float*)d_in[31];
    const float* dec_ff2_b = (const float*)d_in[32];
    const float* dec_ln3_g = (const float*)d_in[33];
    const float* dec_ln3_b = (const float*)d_in[34];
    const float* dec_norm_g = (const float*)d_in[35];
    const float* dec_norm_b = (const float*)d_in[36];
    const float* fc_w = (const float*)d_in[37];
    const float* fc_b = (const float*)d_in[38];

    const int NT = B * STGT;   // 32768
    const int NS = B * SSRC;   // 2048

    // ---- workspace: bf16 activations; fp32 scratch aliases qkv ----
    u16* t_bf    = (u16*)d_ws;                   // 32768*128
    u16* s_bf    = t_bf + (size_t)NT * D;        // 2048*128
    u16* mem_bf  = s_bf + (size_t)NS * D;        // 2048*128
    u16* qkv_bf  = mem_bf + (size_t)NS * D;      // 32768*512
    u16* attno_bf = qkv_bf + (size_t)NT * DFF_;  // 32768*128
    u16* ckv_bf  = attno_bf + (size_t)NT * D;    // 2048*256
    u16* vt      = ckv_bf + (size_t)NS * 2 * D;  // B*NH*16*1024 + pad
    u16* wa      = vt + (size_t)B * NH * 16 * STGT + 16 * STGT;

    u16* w_enc_qkv = wa;                          int n_enc_qkv = LE * 3 * D * D;
    u16* w_enc_out = w_enc_qkv + n_enc_qkv;       int n_enc_out = LE * D * D;
    u16* w_enc_ff1 = w_enc_out + n_enc_out;       int n_enc_ff1 = LE * DFF_ * D;
    u16* w_enc_ff2 = w_enc_ff1 + n_enc_ff1;       int n_enc_ff2 = LE * D * DFF_;
    u16* w_sa_qkv  = w_enc_ff2 + n_enc_ff2;       int n_sa_qkv = LD * 3 * D * D;
    u16* w_sa_out  = w_sa_qkv + n_sa_qkv;         int n_sa_out = LD * D * D;
    u16* w_ca_qkv  = w_sa_out + n_sa_out;         int n_ca_qkv = LD * 3 * D * D;
    u16* w_ca_out  = w_ca_qkv + n_ca_qkv;         int n_ca_out = LD * D * D;
    u16* w_ff1     = w_ca_out + n_ca_out;         int n_ff1 = LD * DFF_ * D;
    u16* w_ff2     = w_ff1 + n_ff1;               int n_ff2 = LD * D * DFF_;

    float* scf = (float*)qkv_bf;  // final-LN fp32 scratch (qkv dead by then)

    CvtJobs jb;
    jb.src[0] = enc_qkv_w;    jb.dst[0] = w_enc_qkv; jb.n[0] = n_enc_qkv;
    jb.src[1] = enc_out_w;    jb.dst[1] = w_enc_out; jb.n[1] = n_enc_out;
    jb.src[2] = enc_ff1_w;    jb.dst[2] = w_enc_ff1; jb.n[2] = n_enc_ff1;
    jb.src[3] = enc_ff2_w;    jb.dst[3] = w_enc_ff2; jb.n[3] = n_enc_ff2;
    jb.src[4] = dec_sa_qkv_w; jb.dst[4] = w_sa_qkv;  jb.n[4] = n_sa_qkv;
    jb.src[5] = dec_sa_out_w; jb.dst[5] = w_sa_out;  jb.n[5] = n_sa_out;
    jb.src[6] = dec_ca_qkv_w; jb.dst[6] = w_ca_qkv;  jb.n[6] = n_ca_qkv;
    jb.src[7] = dec_ca_out_w; jb.dst[7] = w_ca_out;  jb.n[7] = n_ca_out;
    jb.src[8] = dec_ff1_w;    jb.dst[8] = w_ff1;     jb.n[8] = n_ff1;
    jb.src[9] = dec_ff2_w;    jb.dst[9] = w_ff2;     jb.n[9] = n_ff2;
    int maxn = n_enc_ff1;
    hipLaunchKernelGGL(cvt_kernel, dim3((maxn + 255) / 256, 10), dim3(256), 0, stream, jb);

    // ---------------- Encoder ----------------
    hipLaunchKernelGGL(embed_kernel, dim3(NS * D / 256), dim3(256), 0, stream, src, emb, s_bf);

    for (int i = 0; i < LE; i++) {
        gemm_b(s_bf, w_enc_qkv + (size_t)i * 3 * D * D, enc_qkv_b + (size_t)i * 3 * D,
               qkv_bf, NS, 3 * D, D, stream, 128, vt, 256, 6, SSRC);  // Q scaled, V->vt
        hipLaunchKernelGGL((attn3<2>), dim3(B * NH), dim3(128), 0, stream,
                           qkv_bf, 3 * D, qkv_bf, 3 * D, D, vt, attno_bf, SSRC, SSRC);
        gemmln(attno_bf, w_enc_out + (size_t)i * D * D, enc_out_b + (size_t)i * D,
               s_bf, enc_ln1_g + (size_t)i * D, enc_ln1_b + (size_t)i * D, s_bf, NS, D, stream);
        gemm_br(s_bf, w_enc_ff1 + (size_t)i * DFF_ * D, enc_ff1_b + (size_t)i * DFF_,
                qkv_bf, NS, DFF_, D, stream);
        gemmln(qkv_bf, w_enc_ff2 + (size_t)i * D * DFF_, enc_ff2_b + (size_t)i * D,
               s_bf, enc_ln2_g + (size_t)i * D, enc_ln2_b + (size_t)i * D, s_bf, NS, DFF_, stream);
    }
    hipLaunchKernelGGL(ln_bf, dim3(NS), dim3(64), 0, stream,
                       s_bf, enc_norm_g, enc_norm_b, (float*)nullptr, mem_bf);

    // ---------------- Decoder ----------------
    hipLaunchKernelGGL(addpe_kernel, dim3(NT * D / 256), dim3(256), 0, stream, tgt, t_bf);

    for (int i = 0; i < LD; i++) {
        // self-attention
        gemm_b(t_bf, w_sa_qkv + (size_t)i * 3 * D * D, dec_sa_qkv_b + (size_t)i * 3 * D,
               qkv_bf, NT, 3 * D, D, stream, 128, vt, 256, 10, STGT);  // Q scaled, V->vt
        hipLaunchKernelGGL((attn3<4>), dim3(B * NH * (STGT / 128)), dim3(256), 0, stream,
                           qkv_bf, 3 * D, qkv_bf, 3 * D, D, vt, attno_bf, STGT, STGT);
        gemmln(attno_bf, w_sa_out + (size_t)i * D * D, dec_sa_out_b + (size_t)i * D,
               t_bf, dec_ln1_g + (size_t)i * D, dec_ln1_b + (size_t)i * D, t_bf, NT, D, stream);

        // cross-attention
        gemm_b(t_bf, w_ca_qkv + (size_t)i * 3 * D * D, dec_ca_qkv_b + (size_t)i * 3 * D,
               qkv_bf, NT, D, D, stream, 128);  // Q only, pre-scaled
        gemm_b(mem_bf, w_ca_qkv + (size_t)i * 3 * D * D + (size_t)D * D,
               dec_ca_qkv_b + (size_t)i * 3 * D + D, ckv_bf, NS, 2 * D, D, stream,
               0, vt, 128, 6, SSRC);  // K->ckv, V->vt
        hipLaunchKernelGGL((attn3<4>), dim3(B * NH * (STGT / 128)), dim3(256), 0, stream,
                           qkv_bf, D, ckv_bf, 2 * D, 0, vt, attno_bf, STGT, SSRC);
        gemmln(attno_bf, w_ca_out + (size_t)i * D * D, dec_ca_out_b + (size_t)i * D,
               t_bf, dec_ln2_g + (size_t)i * D, dec_ln2_b + (size_t)i * D, t_bf, NT, D, stream);

        // FFN
        gemm_br(t_bf, w_ff1 + (size_t)i * DFF_ * D, dec_ff1_b + (size_t)i * DFF_,
                qkv_bf, NT, DFF_, D, stream);
        gemmln(qkv_bf, w_ff2 + (size_t)i * D * DFF_, dec_ff2_b + (size_t)i * D,
               t_bf, dec_ln3_g + (size_t)i * D, dec_ln3_b + (size_t)i * D, t_bf, NT, DFF_, stream);
    }

    hipLaunchKernelGGL(ln_bf, dim3(NT), dim3(64), 0, stream,
                       t_bf, dec_norm_g, dec_norm_b, scf, (u16*)nullptr);
    hipLaunchKernelGGL(fc_kernel, dim3(NT), dim3(64), 0, stream,
                       scf, fc_w, fc_b, (float*)d_out);
}

// Round 10
// 1363.402 us; speedup vs baseline: 1.4090x; 1.0644x over previous
//
#include <hip/hip_runtime.h>
#include <hip/hip_bf16.h>
#include <stdint.h>

#define NH 8

typedef uint16_t u16;
typedef uint32_t u32;
typedef __attribute__((ext_vector_type(2))) u32 u32x2;
typedef __attribute__((ext_vector_type(8))) short s8b;    // 8 bf16 (4 VGPR)
typedef __attribute__((ext_vector_type(4))) float f32x4;
typedef __attribute__((ext_vector_type(16))) float f32x16;

#if __has_builtin(__builtin_amdgcn_exp2f)
#define EXPS(x) __builtin_amdgcn_exp2f(x)
#define QSCALE 0.36067376022224085f   // 0.25 * log2(e)
#else
#define EXPS(x) __expf(x)
#define QSCALE 0.25f
#endif

// fp32 -> bf16 round-to-nearest-even
__device__ __forceinline__ u16 f2b(float f) {
    u32 u = __builtin_bit_cast(u32, f);
    u = (u + 0x7fffu + ((u >> 16) & 1u)) >> 16;
    return (u16)u;
}
// bf16 -> fp32
__device__ __forceinline__ float b2f(u16 u) {
    return __builtin_bit_cast(float, (u32)u << 16);
}
// pack two fp32 into 2 bf16 (round-half-away): lo=a, hi=b.
__device__ __forceinline__ u32 pkbf(float a, float b) {
    u32 ua = __builtin_bit_cast(u32, a) + 0x8000u;
    u32 ub = __builtin_bit_cast(u32, b) + 0x8000u;
    return __builtin_amdgcn_perm(ub, ua, 0x07060302);  // {ua.hi16, ub.hi16}
}

// PyTorch-style sinusoidal PE
__device__ __forceinline__ float pe_val(int pos, int d) {
    int j = d >> 1;
    float div = expf((float)j * -0.14391156831212787f);
    float ang = (float)pos * div;
    return (d & 1) ? cosf(ang) : sinf(ang);
}

__global__ void embed_kernel(const int* __restrict__ src, const float* __restrict__ emb,
                             u16* __restrict__ Sb) {
    int idx = blockIdx.x * 256 + threadIdx.x;
    int d = idx & 127;
    int n = idx >> 7;
    int i = n & 63;
    int tok = src[n];
    Sb[idx] = f2b(emb[tok * 128 + d] * 11.313708498984761f + pe_val(i, d));
}

__global__ void addpe_kernel(const float* __restrict__ tgt, u16* __restrict__ Tb) {
    int idx = blockIdx.x * 256 + threadIdx.x;
    int d = idx & 127;
    int n = idx >> 7;
    int i = n & 1023;
    Tb[idx] = f2b(tgt[idx] + pe_val(i, d));
}

struct CvtJobs { const float* src[10]; u16* dst[10]; int n[10]; };
__global__ void cvt_kernel(CvtJobs jb) {
    int e = blockIdx.y;
    int i = blockIdx.x * 256 + threadIdx.x;
    if (i < jb.n[e]) jb.dst[e][i] = f2b(jb.src[e][i]);
}

// ---------------------------------------------------------------------------
// LDS-staged MFMA GEMM with register prefetch of the next k-tile.
// C[m,n] = sum_k A[m,k]*W[n,k]+bias. 128x128 tile, 4 waves x 64x64.
// Optional qscale on cols<qcols; optional RELU; optional fused V-transpose.
template <int RELU>
__global__ __launch_bounds__(256) void gemm_mfma(
    const u16* __restrict__ A, const u16* __restrict__ W,
    const float* __restrict__ bias, u16* __restrict__ C,
    int M, int N, int K, float qscale, int qcols,
    u16* __restrict__ vt, int vcol0, int sshift, int smask, int skv) {
    __shared__ __align__(16) u16 As[128 * 56];
    __shared__ __align__(16) u16 Bs[128 * 56];
    int tid = threadIdx.x;
    int lane = tid & 63, w = tid >> 6;
    int quad = lane >> 4, l15 = lane & 15;
    int m0 = blockIdx.y * 128, n0 = blockIdx.x * 128;
    int wm = (w & 1) * 64, wn = (w >> 1) * 64;
    int srow = tid >> 1, skof = (tid & 1) * 16;

    f32x4 acc[4][4];
#pragma unroll
    for (int i = 0; i < 4; i++)
#pragma unroll
        for (int j = 0; j < 4; j++)
#pragma unroll
            for (int r = 0; r < 4; r++) acc[i][j][r] = 0.f;

    const u16* ga = A + (size_t)(m0 + srow) * K + skof;
    const u16* gw = W + (size_t)(n0 + srow) * K + skof;
    s8b a0 = *(const s8b*)ga, a1 = *(const s8b*)(ga + 8);
    s8b w0 = *(const s8b*)gw, w1 = *(const s8b*)(gw + 8);

    for (int k0 = 0; k0 < K; k0 += 32) {
        __syncthreads();
        *(s8b*)(As + srow * 56 + skof) = a0;
        *(s8b*)(As + srow * 56 + skof + 8) = a1;
        *(s8b*)(Bs + srow * 56 + skof) = w0;
        *(s8b*)(Bs + srow * 56 + skof + 8) = w1;
        __syncthreads();
        if (k0 + 32 < K) {   // prefetch next k-tile; overlaps frag reads + MFMA
            a0 = *(const s8b*)(ga + k0 + 32); a1 = *(const s8b*)(ga + k0 + 40);
            w0 = *(const s8b*)(gw + k0 + 32); w1 = *(const s8b*)(gw + k0 + 40);
        }
        s8b af[4], bfr[4];
#pragma unroll
        for (int i = 0; i < 4; i++) af[i] = *(const s8b*)(As + (wm + 16 * i + l15) * 56 + quad * 8);
#pragma unroll
        for (int j = 0; j < 4; j++) bfr[j] = *(const s8b*)(Bs + (wn + 16 * j + l15) * 56 + quad * 8);
#pragma unroll
        for (int i = 0; i < 4; i++)
#pragma unroll
            for (int j = 0; j < 4; j++)
                acc[i][j] = __builtin_amdgcn_mfma_f32_16x16x32_bf16(af[i], bfr[j], acc[i][j], 0, 0, 0);
    }

    if (vt && n0 == vcol0) {
        // V-block: write transposed to vt. C rows quad*4..+3 = consecutive tokens.
#pragma unroll
        for (int j = 0; j < 4; j++) {
            int lc = wn + 16 * j + l15;
            int h = lc >> 4, n = lc & 15;
            float bv = bias[vcol0 + lc];
#pragma unroll
            for (int i = 0; i < 4; i++) {
                int row = m0 + wm + 16 * i + quad * 4;
                int b = row >> sshift, tok = row & smask;
                u32 lo = pkbf(acc[i][j][0] + bv, acc[i][j][1] + bv);
                u32 hi = pkbf(acc[i][j][2] + bv, acc[i][j][3] + bv);
                u32* p = (u32*)(vt + ((size_t)((b * 8 + h) * 16 + n)) * skv + tok);
                p[0] = lo; p[1] = hi;
            }
        }
        return;
    }
#pragma unroll
    for (int j = 0; j < 4; j++) {
        int col = n0 + wn + 16 * j + l15;
        float bv = bias[col];
        float sc = (col < qcols) ? qscale : 1.f;
#pragma unroll
        for (int i = 0; i < 4; i++) {
            int rbase = m0 + wm + 16 * i + quad * 4;
#pragma unroll
            for (int r = 0; r < 4; r++) {
                float v = (acc[i][j][r] + bv) * sc;
                if (RELU) v = fmaxf(v, 0.f);
                C[(size_t)(rbase + r) * N + col] = f2b(v);
            }
        }
    }
}

// ---------------------------------------------------------------------------
// LDS-staged GEMM (N=128) fused with residual-add + LayerNorm; bf16 residual
// stream; register prefetch of next k-tile.
__global__ __launch_bounds__(256) void gemm_ln(
    const u16* __restrict__ A, const u16* __restrict__ W,
    const float* __restrict__ bias, const u16* __restrict__ X,
    const float* __restrict__ g, const float* __restrict__ bta,
    u16* __restrict__ Yb, int M, int K) {
    __shared__ __align__(16) u16 As[128 * 56];
    __shared__ __align__(16) u16 Bs[128 * 56];
    __shared__ float redS[128][2], redQ[128][2];
    int tid = threadIdx.x;
    int lane = tid & 63, w = tid >> 6;
    int quad = lane >> 4, l15 = lane & 15;
    int m0 = blockIdx.x * 128;
    int wm = (w & 1) * 64, wn = (w >> 1) * 64;
    int srow = tid >> 1, skof = (tid & 1) * 16;

    f32x4 acc[4][4];
#pragma unroll
    for (int i = 0; i < 4; i++)
#pragma unroll
        for (int j = 0; j < 4; j++)
#pragma unroll
            for (int r = 0; r < 4; r++) acc[i][j][r] = 0.f;

    const u16* ga = A + (size_t)(m0 + srow) * K + skof;
    const u16* gw = W + (size_t)srow * K + skof;
    s8b a0 = *(const s8b*)ga, a1 = *(const s8b*)(ga + 8);
    s8b w0 = *(const s8b*)gw, w1 = *(const s8b*)(gw + 8);

    for (int k0 = 0; k0 < K; k0 += 32) {
        __syncthreads();
        *(s8b*)(As + srow * 56 + skof) = a0;
        *(s8b*)(As + srow * 56 + skof + 8) = a1;
        *(s8b*)(Bs + srow * 56 + skof) = w0;
        *(s8b*)(Bs + srow * 56 + skof + 8) = w1;
        __syncthreads();
        if (k0 + 32 < K) {
            a0 = *(const s8b*)(ga + k0 + 32); a1 = *(const s8b*)(ga + k0 + 40);
            w0 = *(const s8b*)(gw + k0 + 32); w1 = *(const s8b*)(gw + k0 + 40);
        }
        s8b af[4], bfr[4];
#pragma unroll
        for (int i = 0; i < 4; i++) af[i] = *(const s8b*)(As + (wm + 16 * i + l15) * 56 + quad * 8);
#pragma unroll
        for (int j = 0; j < 4; j++) bfr[j] = *(const s8b*)(Bs + (wn + 16 * j + l15) * 56 + quad * 8);
#pragma unroll
        for (int i = 0; i < 4; i++)
#pragma unroll
            for (int j = 0; j < 4; j++)
                acc[i][j] = __builtin_amdgcn_mfma_f32_16x16x32_bf16(af[i], bfr[j], acc[i][j], 0, 0, 0);
    }

    float s_[4][4], q_[4][4];
#pragma unroll
    for (int i = 0; i < 4; i++)
#pragma unroll
        for (int r = 0; r < 4; r++) {
            int row = m0 + wm + 16 * i + quad * 4 + r;
            float s = 0.f, q = 0.f;
#pragma unroll
            for (int j = 0; j < 4; j++) {
                int col = wn + 16 * j + l15;
                float x = acc[i][j][r] + bias[col] + b2f(X[(size_t)row * 128 + col]);
                acc[i][j][r] = x;
                s += x; q += x * x;
            }
#pragma unroll
            for (int off = 1; off < 16; off <<= 1) {
                s += __shfl_xor(s, off);
                q += __shfl_xor(q, off);
            }
            s_[i][r] = s; q_[i][r] = q;
        }
    if (l15 == 0) {
#pragma unroll
        for (int i = 0; i < 4; i++)
#pragma unroll
            for (int r = 0; r < 4; r++) {
                int lrow = wm + 16 * i + quad * 4 + r;
                redS[lrow][wn >> 6] = s_[i][r];
                redQ[lrow][wn >> 6] = q_[i][r];
            }
    }
    __syncthreads();
#pragma unroll
    for (int i = 0; i < 4; i++)
#pragma unroll
        for (int r = 0; r < 4; r++) {
            int lrow = wm + 16 * i + quad * 4 + r;
            int row = m0 + lrow;
            float S2 = redS[lrow][0] + redS[lrow][1];
            float Q2 = redQ[lrow][0] + redQ[lrow][1];
            float mean = S2 * (1.f / 128.f);
            float var = Q2 * (1.f / 128.f) - mean * mean;
            float rstd = rsqrtf(var + 1e-5f);
#pragma unroll
            for (int j = 0; j < 4; j++) {
                int col = wn + 16 * j + l15;
                float y = (acc[i][j][r] - mean) * rstd * g[col] + bta[col];
                Yb[(size_t)row * 128 + col] = f2b(y);
            }
        }
}

// MFMA flash attention v3; loop-invariant zero C-operand for the S MFMA.
template <int WAVES>
__global__ __launch_bounds__(WAVES * 64) void attn3(
    const u16* __restrict__ Qb, int qstride,
    const u16* __restrict__ Kb, int kstride, int koff,
    const u16* __restrict__ VT,
    u16* __restrict__ O, int SQ, int SKV) {
    __shared__ __align__(16) u32 Ps[WAVES][32 * 20];
    int tid = threadIdx.x;
    int lane = tid & 63, w = tid >> 6;
    int quad = lane >> 4, l15 = lane & 15, l31 = lane & 31, half = lane >> 5;
    int nqc = SQ / (WAVES * 32);
    int bid = blockIdx.x;
    int qc = bid % nqc;
    int h = (bid / nqc) % NH;
    int b = bid / (nqc * NH);
    int q0 = qc * WAVES * 32 + w * 32;

    const u16* qp = Qb + (size_t)(b * SQ + q0 + l31) * qstride + h * 16 + half * 8;
    s8b qf = *(const s8b*)qp;
    s8b ones;
#pragma unroll
    for (int j = 0; j < 8; j++) ones[j] = (short)0x3F80;  // bf16 1.0

    const u16* vtb = VT + ((size_t)(b * NH + h) * 16 + l15) * SKV + quad * 8;
    const u16* kp = Kb + (size_t)(b * SKV + l31) * kstride + koff + h * 16 + half * 8;
    size_t kadv = (size_t)32 * kstride;

    f32x4 O0, O1, L0, L1;
#pragma unroll
    for (int r = 0; r < 4; r++) { O0[r] = 0.f; O1[r] = 0.f; L0[r] = 0.f; L1[r] = 0.f; }
    f32x16 z16;   // loop-invariant zero accumulator (no per-tile re-init)
#pragma unroll
    for (int r = 0; r < 16; r++) z16[r] = 0.f;

    u32* pw = Ps[w];
#pragma unroll 2
    for (int j0 = 0; j0 < SKV; j0 += 32) {
        s8b kf = *(const s8b*)kp;
        kp += kadv;
        s8b vb = *(const s8b*)(vtb + j0);
        f32x16 S = __builtin_amdgcn_mfma_f32_32x32x16_bf16(kf, qf, z16, 0, 0, 0);  // S^T
        // C-layout: col = q = lane&31; row = key = (r&3) + 8*(r>>2) + 4*half
#pragma unroll
        for (int g = 0; g < 4; g++) {
            float p0 = EXPS(S[4 * g + 0]);
            float p1 = EXPS(S[4 * g + 1]);
            float p2 = EXPS(S[4 * g + 2]);
            float p3 = EXPS(S[4 * g + 3]);
            u32x2 pk;
            pk[0] = pkbf(p0, p1);
            pk[1] = pkbf(p2, p3);
            *(u32x2*)(pw + l31 * 20 + 2 * half + 4 * g) = pk;  // ds_write_b64
        }
        __builtin_amdgcn_wave_barrier();  // wave-private LDS RAW ordering
        s8b pa0 = *(const s8b*)(pw + l15 * 20 + quad * 4);
        s8b pa1 = *(const s8b*)(pw + (16 + l15) * 20 + quad * 4);
        O0 = __builtin_amdgcn_mfma_f32_16x16x32_bf16(pa0, vb, O0, 0, 0, 0);
        O1 = __builtin_amdgcn_mfma_f32_16x16x32_bf16(pa1, vb, O1, 0, 0, 0);
        L0 = __builtin_amdgcn_mfma_f32_16x16x32_bf16(pa0, ones, L0, 0, 0, 0);
        L1 = __builtin_amdgcn_mfma_f32_16x16x32_bf16(pa1, ones, L1, 0, 0, 0);
    }
#pragma unroll
    for (int r = 0; r < 4; r++) {
        int q = b * SQ + q0 + quad * 4 + r;
        O[(size_t)q * 128 + h * 16 + l15] = f2b(O0[r] / L0[r]);
        O[(size_t)(q + 16) * 128 + h * 16 + l15] = f2b(O1[r] / L1[r]);
    }
}

// Standalone LN over 128 cols, bf16 input -> bf16 output.
__global__ void ln_bf(const u16* __restrict__ X,
                      const float* __restrict__ g, const float* __restrict__ bta,
                      u16* __restrict__ Yb) {
    int r = blockIdx.x;
    int lane = threadIdx.x;
    size_t base = (size_t)r * 128;
    float x0 = b2f(X[base + lane]), x1 = b2f(X[base + lane + 64]);
    float s = x0 + x1;
    for (int off = 32; off; off >>= 1) s += __shfl_xor(s, off);
    float mean = s * (1.f / 128.f);
    float d0 = x0 - mean, d1 = x1 - mean;
    float vs = d0 * d0 + d1 * d1;
    for (int off = 32; off; off >>= 1) vs += __shfl_xor(vs, off);
    float rstd = rsqrtf(vs * (1.f / 128.f) + 1e-5f);
    Yb[base + lane] = f2b(d0 * rstd * g[lane] + bta[lane]);
    Yb[base + lane + 64] = f2b(d1 * rstd * g[lane + 64] + bta[lane + 64]);
}

// Fused final LayerNorm + FC (out[r] = dot(LN(X[r,:]), w) + b), one wave/row.
__global__ void ln_fc(const u16* __restrict__ X,
                      const float* __restrict__ g, const float* __restrict__ bta,
                      const float* __restrict__ w, const float* __restrict__ bb,
                      float* __restrict__ out) {
    int r = blockIdx.x;
    int lane = threadIdx.x;
    size_t base = (size_t)r * 128;
    float x0 = b2f(X[base + lane]), x1 = b2f(X[base + lane + 64]);
    float s = x0 + x1;
    for (int off = 32; off; off >>= 1) s += __shfl_xor(s, off);
    float mean = s * (1.f / 128.f);
    float d0 = x0 - mean, d1 = x1 - mean;
    float vs = d0 * d0 + d1 * d1;
    for (int off = 32; off; off >>= 1) vs += __shfl_xor(vs, off);
    float rstd = rsqrtf(vs * (1.f / 128.f) + 1e-5f);
    float y0 = d0 * rstd * g[lane] + bta[lane];
    float y1 = d1 * rstd * g[lane + 64] + bta[lane + 64];
    float acc = y0 * w[lane] + y1 * w[lane + 64];
    for (int off = 32; off; off >>= 1) acc += __shfl_xor(acc, off);
    if (lane == 0) out[r] = acc + bb[0];
}

// ---- launch helpers ----
static inline void gemm_b(const u16* A, const u16* W, const float* bias, u16* C,
                          int M, int N, int K, hipStream_t st, int qcols = 0,
                          u16* vt = nullptr, int vcol0 = 0, int sshift = 0, int skv = 0) {
    hipLaunchKernelGGL((gemm_mfma<0>), dim3(N / 128, M / 128), dim3(256), 0, st,
                       A, W, bias, C, M, N, K, QSCALE, qcols, vt, vcol0, sshift,
                       (1 << sshift) - 1, skv);
}
static inline void gemm_br(const u16* A, const u16* W, const float* bias, u16* C,
                           int M, int N, int K, hipStream_t st) {
    hipLaunchKernelGGL((gemm_mfma<1>), dim3(N / 128, M / 128), dim3(256), 0, st,
                       A, W, bias, C, M, N, K, 1.f, 0, (u16*)nullptr, 0, 0, 0, 0);
}
static inline void gemmln(const u16* A, const u16* W, const float* bias,
                          const u16* X, const float* g, const float* bta,
                          u16* Yb, int M, int K, hipStream_t st) {
    hipLaunchKernelGGL(gemm_ln, dim3(M / 128), dim3(256), 0, st,
                       A, W, bias, X, g, bta, Yb, M, K);
}

extern "C" void kernel_launch(void* const* d_in, const int* in_sizes, int n_in,
                              void* d_out, int out_size, void* d_ws, size_t ws_size,
                              hipStream_t stream) {
    const int B = 32, SSRC = 64, STGT = 1024, D = 128, DFF_ = 512, LE = 6, LD = 6;

    const int*   src = (const int*)d_in[0];
    const float* tgt = (const float*)d_in[1];
    const float* emb = (const float*)d_in[2];
    const float* enc_qkv_w = (const float*)d_in[3];
    const float* enc_qkv_b = (const float*)d_in[4];
    const float* enc_out_w = (const float*)d_in[5];
    const float* enc_out_b = (const float*)d_in[6];
    const float* enc_ln1_g = (const float*)d_in[7];
    const float* enc_ln1_b = (const float*)d_in[8];
    const float* enc_ff1_w = (const float*)d_in[9];
    const float* enc_ff1_b = (const float*)d_in[10];
    const float* enc_ff2_w = (const float*)d_in[11];
    const float* enc_ff2_b = (const float*)d_in[12];
    const float* enc_ln2_g = (const float*)d_in[13];
    const float* enc_ln2_b = (const float*)d_in[14];
    const float* enc_norm_g = (const float*)d_in[15];
    const float* enc_norm_b = (const float*)d_in[16];
    const float* dec_sa_qkv_w = (const float*)d_in[17];
    const float* dec_sa_qkv_b = (const float*)d_in[18];
    const float* dec_sa_out_w = (const float*)d_in[19];
    const float* dec_sa_out_b = (const float*)d_in[20];
    const float* dec_ln1_g = (const float*)d_in[21];
    const float* dec_ln1_b = (const float*)d_in[22];
    const float* dec_ca_qkv_w = (const float*)d_in[23];
    const float* dec_ca_qkv_b = (const float*)d_in[24];
    const float* dec_ca_out_w = (const float*)d_in[25];
    const float* dec_ca_out_b = (const float*)d_in[26];
    const float* dec_ln2_g = (const float*)d_in[27];
    const float* dec_ln2_b = (const float*)d_in[28];
    const float* dec_ff1_w = (const float*)d_in[29];
    const float* dec_ff1_b = (const float*)d_in[30];
    const float* dec_ff2_w = (const float*)d_in[31];
    const float* dec_ff2_b = (const float*)d_in[32];
    const float* dec_ln3_g = (const float*)d_in[33];
    const float* dec_ln3_b = (const float*)d_in[34];
    const float* dec_norm_g = (const float*)d_in[35];
    const float* dec_norm_b = (const float*)d_in[36];
    const float* fc_w = (const float*)d_in[37];
    const float* fc_b = (const float*)d_in[38];

    const int NT = B * STGT;   // 32768
    const int NS = B * SSRC;   // 2048

    // ---- workspace: bf16 activations ----
    u16* t_bf    = (u16*)d_ws;                   // 32768*128
    u16* s_bf    = t_bf + (size_t)NT * D;        // 2048*128
    u16* mem_bf  = s_bf + (size_t)NS * D;        // 2048*128
    u16* qkv_bf  = mem_bf + (size_t)NS * D;      // 32768*512
    u16* attno_bf = qkv_bf + (size_t)NT * DFF_;  // 32768*128
    u16* ckv_bf  = attno_bf + (size_t)NT * D;    // 2048*256
    u16* vt      = ckv_bf + (size_t)NS * 2 * D;  // B*NH*16*1024 + pad
    u16* wa      = vt + (size_t)B * NH * 16 * STGT + 16 * STGT;

    u16* w_enc_qkv = wa;                          int n_enc_qkv = LE * 3 * D * D;
    u16* w_enc_out = w_enc_qkv + n_enc_qkv;       int n_enc_out = LE * D * D;
    u16* w_enc_ff1 = w_enc_out + n_enc_out;       int n_enc_ff1 = LE * DFF_ * D;
    u16* w_enc_ff2 = w_enc_ff1 + n_enc_ff1;       int n_enc_ff2 = LE * D * DFF_;
    u16* w_sa_qkv  = w_enc_ff2 + n_enc_ff2;       int n_sa_qkv = LD * 3 * D * D;
    u16* w_sa_out  = w_sa_qkv + n_sa_qkv;         int n_sa_out = LD * D * D;
    u16* w_ca_qkv  = w_sa_out + n_sa_out;         int n_ca_qkv = LD * 3 * D * D;
    u16* w_ca_out  = w_ca_qkv + n_ca_qkv;         int n_ca_out = LD * D * D;
    u16* w_ff1     = w_ca_out + n_ca_out;         int n_ff1 = LD * DFF_ * D;
    u16* w_ff2     = w_ff1 + n_ff1;               int n_ff2 = LD * D * DFF_;

    CvtJobs jb;
    jb.src[0] = enc_qkv_w;    jb.dst[0] = w_enc_qkv; jb.n[0] = n_enc_qkv;
    jb.src[1] = enc_out_w;    jb.dst[1] = w_enc_out; jb.n[1] = n_enc_out;
    jb.src[2] = enc_ff1_w;    jb.dst[2] = w_enc_ff1; jb.n[2] = n_enc_ff1;
    jb.src[3] = enc_ff2_w;    jb.dst[3] = w_enc_ff2; jb.n[3] = n_enc_ff2;
    jb.src[4] = dec_sa_qkv_w; jb.dst[4] = w_sa_qkv;  jb.n[4] = n_sa_qkv;
    jb.src[5] = dec_sa_out_w; jb.dst[5] = w_sa_out;  jb.n[5] = n_sa_out;
    jb.src[6] = dec_ca_qkv_w; jb.dst[6] = w_ca_qkv;  jb.n[6] = n_ca_qkv;
    jb.src[7] = dec_ca_out_w; jb.dst[7] = w_ca_out;  jb.n[7] = n_ca_out;
    jb.src[8] = dec_ff1_w;    jb.dst[8] = w_ff1;     jb.n[8] = n_ff1;
    jb.src[9] = dec_ff2_w;    jb.dst[9] = w_ff2;     jb.n[9] = n_ff2;
    int maxn = n_enc_ff1;
    hipLaunchKernelGGL(cvt_kernel, dim3((maxn + 255) / 256, 10), dim3(256), 0, stream, jb);

    // ---------------- Encoder ----------------
    hipLaunchKernelGGL(embed_kernel, dim3(NS * D / 256), dim3(256), 0, stream, src, emb, s_bf);

    for (int i = 0; i < LE; i++) {
        gemm_b(s_bf, w_enc_qkv + (size_t)i * 3 * D * D, enc_qkv_b + (size_t)i * 3 * D,
               qkv_bf, NS, 3 * D, D, stream, 128, vt, 256, 6, SSRC);  // Q scaled, V->vt
        hipLaunchKernelGGL((attn3<2>), dim3(B * NH), dim3(128), 0, stream,
                           qkv_bf, 3 * D, qkv_bf, 3 * D, D, vt, attno_bf, SSRC, SSRC);
        gemmln(attno_bf, w_enc_out + (size_t)i * D * D, enc_out_b + (size_t)i * D,
               s_bf, enc_ln1_g + (size_t)i * D, enc_ln1_b + (size_t)i * D, s_bf, NS, D, stream);
        gemm_br(s_bf, w_enc_ff1 + (size_t)i * DFF_ * D, enc_ff1_b + (size_t)i * DFF_,
                qkv_bf, NS, DFF_, D, stream);
        gemmln(qkv_bf, w_enc_ff2 + (size_t)i * D * DFF_, enc_ff2_b + (size_t)i * D,
               s_bf, enc_ln2_g + (size_t)i * D, enc_ln2_b + (size_t)i * D, s_bf, NS, DFF_, stream);
    }
    hipLaunchKernelGGL(ln_bf, dim3(NS), dim3(64), 0, stream,
                       s_bf, enc_norm_g, enc_norm_b, mem_bf);

    // ---------------- Decoder ----------------
    hipLaunchKernelGGL(addpe_kernel, dim3(NT * D / 256), dim3(256), 0, stream, tgt, t_bf);

    for (int i = 0; i < LD; i++) {
        // self-attention
        gemm_b(t_bf, w_sa_qkv + (size_t)i * 3 * D * D, dec_sa_qkv_b + (size_t)i * 3 * D,
               qkv_bf, NT, 3 * D, D, stream, 128, vt, 256, 10, STGT);  // Q scaled, V->vt
        hipLaunchKernelGGL((attn3<4>), dim3(B * NH * (STGT / 128)), dim3(256), 0, stream,
                           qkv_bf, 3 * D, qkv_bf, 3 * D, D, vt, attno_bf, STGT, STGT);
        gemmln(attno_bf, w_sa_out + (size_t)i * D * D, dec_sa_out_b + (size_t)i * D,
               t_bf, dec_ln1_g + (size_t)i * D, dec_ln1_b + (size_t)i * D, t_bf, NT, D, stream);

        // cross-attention
        gemm_b(t_bf, w_ca_qkv + (size_t)i * 3 * D * D, dec_ca_qkv_b + (size_t)i * 3 * D,
               qkv_bf, NT, D, D, stream, 128);  // Q only, pre-scaled
        gemm_b(mem_bf, w_ca_qkv + (size_t)i * 3 * D * D + (size_t)D * D,
               dec_ca_qkv_b + (size_t)i * 3 * D + D, ckv_bf, NS, 2 * D, D, stream,
               0, vt, 128, 6, SSRC);  // K->ckv, V->vt
        hipLaunchKernelGGL((attn3<4>), dim3(B * NH * (STGT / 128)), dim3(256), 0, stream,
                           qkv_bf, D, ckv_bf, 2 * D, 0, vt, attno_bf, STGT, SSRC);
        gemmln(attno_bf, w_ca_out + (size_t)i * D * D, dec_ca_out_b + (size_t)i * D,
               t_bf, dec_ln2_g + (size_t)i * D, dec_ln2_b + (size_t)i * D, t_bf, NT, D, stream);

        // FFN
        gemm_br(t_bf, w_ff1 + (size_t)i * DFF_ * D, dec_ff1_b + (size_t)i * DFF_,
                qkv_bf, NT, DFF_, D, stream);
        gemmln(qkv_bf, w_ff2 + (size_t)i * D * DFF_, dec_ff2_b + (size_t)i * D,
               t_bf, dec_ln3_g + (size_t)i * D, dec_ln3_b + (size_t)i * D, t_bf, NT, DFF_, stream);
    }

    hipLaunchKernelGGL(ln_fc, dim3(NT), dim3(64), 0, stream,
                       t_bf, dec_norm_g, dec_norm_b, fc_w, fc_b, (float*)d_out);
}